// Round 14
// baseline (217.737 us; speedup 1.0000x reference)
//
#include <hip/hip_runtime.h>

#define NT 256
#define NF 512        // threads for fused scatter+gemm (8 waves)
#define NB 1024       // threads for bcsr (16 waves)
#define TILE 256      // nodes per bucket
#define TILE_SH 8
#define BSTRIDE 8192  // padded edge slots per bucket (mean 4096, sigma 64)
#define BSTRIDE_SH 13
#define EPB 4096      // edges per block in bucket scatter pass
#define ITB 8         // EPB / NF
#define NBUCK_PAD 512
#define GTILE 128     // nodes per fused-gemm tile (8 waves x 16 rows)

static inline int cdiv(long long a, long long b) { return (int)((a + b - 1) / b); }

typedef unsigned int uint32;
typedef unsigned short ushort16;
typedef short bf16x8 __attribute__((ext_vector_type(8)));
typedef float f32x4 __attribute__((ext_vector_type(4)));

__device__ __forceinline__ ushort16 f2bf(float f) {
  uint32 u = __float_as_uint(f);
  u = (u + 0x7FFF + ((u >> 16) & 1)) >> 16;  // round-to-nearest-even
  return (ushort16)u;
}
__device__ __forceinline__ float bflo(uint32 w) { return __uint_as_float(w << 16); }
__device__ __forceinline__ float bfhi(uint32 w) { return __uint_as_float(w & 0xFFFF0000u); }
__device__ __forceinline__ float bf2f(ushort16 h) { return __uint_as_float(((uint32)h) << 16); }

// stage W (fp32 [k][64]) -> bf16 transposed Wt[n][k], row stride K+8
template <int K, int NTH>
__device__ __forceinline__ void stage_W(const float* __restrict__ W,
                                        unsigned short* __restrict__ Wt) {
  constexpr int STR = K + 8;
  for (int i = threadIdx.x; i < K * 64; i += NTH) {
    int k = i >> 6, nn = i & 63;
    Wt[nn * STR + k] = f2bf(W[i]);
  }
}

// ---- MFMA GEMM tile for 512-thr blocks: 128 nodes (wave w -> rows w*16..+16),
// fp32 X direct-to-register + hi/lo bf16 split, 2 chained MFMAs.
// D = mfma(W_frag, X_frag): C/D col (lane&15) = node, row (quad*4+reg) = out-dim.
// No cross-wave coupling and no barriers: waves pipeline tiles independently.
template <int K>
__device__ __forceinline__ void gemm_tile8(const float* __restrict__ Xp,
                                           const unsigned short* __restrict__ Wt,
                                           uint2* __restrict__ Yb, int n, int base) {
  constexpr int STR = K + 8;
  const int tid = threadIdx.x;
  const int w = tid >> 6;  // 0..7
  const int lane = tid & 63;
  const int r = lane & 15;
  const int quad = lane >> 4;
  const int v = base + w * 16 + r;

  f32x4 acc[4];
#pragma unroll
  for (int i = 0; i < 4; ++i) acc[i] = (f32x4)(0.f);

  const float4* X4 = (const float4*)Xp;  // K/4 float4 per row
  float4 a[K / 32][2];
#pragma unroll
  for (int ks = 0; ks < K / 32; ++ks) {
    a[ks][0] = make_float4(0.f, 0.f, 0.f, 0.f);
    a[ks][1] = make_float4(0.f, 0.f, 0.f, 0.f);
    if (v < n) {
      a[ks][0] = X4[(size_t)v * (K / 4) + ks * 8 + quad * 2];
      a[ks][1] = X4[(size_t)v * (K / 4) + ks * 8 + quad * 2 + 1];
    }
  }
#pragma unroll
  for (int ks = 0; ks < K / 32; ++ks) {
    float f[8] = {a[ks][0].x, a[ks][0].y, a[ks][0].z, a[ks][0].w,
                  a[ks][1].x, a[ks][1].y, a[ks][1].z, a[ks][1].w};
    bf16x8 xh, xl;
#pragma unroll
    for (int j = 0; j < 8; ++j) {
      ushort16 h = f2bf(f[j]);
      xh[j] = (short)h;
      xl[j] = (short)f2bf(f[j] - bf2f(h));
    }
    const int koff = ks * 32 + quad * 8;
#pragma unroll
    for (int nt = 0; nt < 4; ++nt) {
      bf16x8 wf = *(const bf16x8*)&Wt[(nt * 16 + r) * STR + koff];
      acc[nt] = __builtin_amdgcn_mfma_f32_16x16x32_bf16(wf, xl, acc[nt], 0, 0, 0);
      acc[nt] = __builtin_amdgcn_mfma_f32_16x16x32_bf16(wf, xh, acc[nt], 0, 0, 0);
    }
  }

  if (v < n) {
#pragma unroll
    for (int nt = 0; nt < 4; ++nt) {
      // reg i holds out-dim nt*16 + quad*4 + i for node v
      uint2 u;
      u.x = (uint32)f2bf(acc[nt][0]) | ((uint32)f2bf(acc[nt][1]) << 16);
      u.y = (uint32)f2bf(acc[nt][2]) | ((uint32)f2bf(acc[nt][3]) << 16);
      Yb[(size_t)v * 16 + nt * 4 + quad] = u;
    }
  }
}

// ---- MFMA tile for 256-thr gather_l1 blocks (4 waves): 32 nodes.
// wave w -> row half (w&1), out-dim half (w>>1). A-rows (bf16) from LDS. ----
template <int K>
__device__ __forceinline__ void gemm_tile_lds4(const unsigned short* __restrict__ Hs,
                                               const unsigned short* __restrict__ Wt,
                                               uint2* __restrict__ Yb, int n,
                                               int base) {
  constexpr int STR = K + 8;
  const int tid = threadIdx.x;
  const int w = tid >> 6;   // 0..3
  const int wr = w & 1;     // row half
  const int nh = w >> 1;    // out-dim half
  const int lane = tid & 63;
  const int r = lane & 15;
  const int quad = lane >> 4;
  const int rloc = wr * 16 + r;
  const int v = base + rloc;

  f32x4 acc[2];
#pragma unroll
  for (int i = 0; i < 2; ++i) acc[i] = (f32x4)(0.f);
#pragma unroll
  for (int ks = 0; ks < K / 32; ++ks) {
    const int koff = ks * 32 + quad * 8;
    bf16x8 xf = *(const bf16x8*)&Hs[rloc * STR + koff];
#pragma unroll
    for (int i = 0; i < 2; ++i) {
      const int nt = nh * 2 + i;
      bf16x8 wf = *(const bf16x8*)&Wt[(nt * 16 + r) * STR + koff];
      acc[i] = __builtin_amdgcn_mfma_f32_16x16x32_bf16(wf, xf, acc[i], 0, 0, 0);
    }
  }
  if (v < n) {
#pragma unroll
    for (int i = 0; i < 2; ++i) {
      const int nt = nh * 2 + i;
      uint2 u;
      u.x = (uint32)f2bf(acc[i][0]) | ((uint32)f2bf(acc[i][1]) << 16);
      u.y = (uint32)f2bf(acc[i][2]) | ((uint32)f2bf(acc[i][3]) << 16);
      Yb[(size_t)v * 16 + nt * 4 + quad] = u;
    }
  }
}

struct ScatSh {
  int cnt[NBUCK_PAD];
  int lcur[NBUCK_PAD];
  int delta[NBUCK_PAD];
  int hs[NF];
  uint32 sorted[EPB];
  unsigned short bid[EPB];
};
union FusedSh {
  unsigned short wt[64 * 136];  // 17.4 KB
  ScatSh s;                     // 32 KB -> union 32 KB, 4 blocks/CU (128 KB LDS)
};

// Fused launch (grid 1024 x 512 thr, 4 blocks/CU = full 32-wave residency):
// blocks [0, gscat=391) do the bucketed edge scatter with 8 waves each, then
// statically sweep the GEMM tile tail [T0, ntile). Blocks [gscat, 1024)
// grid-stride GEMM tiles [0, T0) -- static assignment, zero steal traffic,
// zero barriers between tiles (measured fastest structure; block-chunk steal,
// per-wave steal, and EPB split all measured slower in rounds 6-8).
__global__ __launch_bounds__(NF) void k_fused(
    const int* __restrict__ src, const int* __restrict__ dst,
    int* __restrict__ bcursor, uint32* __restrict__ buck, int nE, int nbuck,
    int gscat, int t0, int ntile, const float* __restrict__ X,
    const float* __restrict__ W1, uint2* __restrict__ Yb, int n) {
  __shared__ FusedSh sm;
  const int t = threadIdx.x;
  const bool isScat = (int)blockIdx.x < gscat;
  if (isScat) {
    sm.s.cnt[t] = 0;
    __syncthreads();
    const int e0 = blockIdx.x * EPB;
    const int ne = min(EPB, nE - e0);
    int dreg[ITB];
#pragma unroll
    for (int it = 0; it < ITB; ++it) {
      int e = e0 + it * NF + t;
      dreg[it] = (e < nE) ? dst[e] : -1;
      if (dreg[it] >= 0) atomicAdd(&sm.s.cnt[dreg[it] >> TILE_SH], 1);
    }
    __syncthreads();
    // exclusive scan over 512 counters: one bucket per thread, Hillis-Steele
    int c = sm.s.cnt[t];
    sm.s.hs[t] = c;
    __syncthreads();
    for (int o = 1; o < NF; o <<= 1) {
      int x = (t >= o) ? sm.s.hs[t - o] : 0;
      __syncthreads();
      sm.s.hs[t] += x;
      __syncthreads();
    }
    int lb = sm.s.hs[t] - c;  // exclusive base of bucket t
    sm.s.lcur[t] = lb;
    if (t < nbuck) {
      int g = c ? atomicAdd(&bcursor[t], c) : 0;
      sm.s.delta[t] = (t << BSTRIDE_SH) + g - lb;
    }
    __syncthreads();
#pragma unroll
    for (int it = 0; it < ITB; ++it) {
      int e = e0 + it * NF + t;
      if (dreg[it] >= 0) {
        int d = dreg[it];
        int b = d >> TILE_SH;
        int p = atomicAdd(&sm.s.lcur[b], 1);  // p < ne <= EPB by construction
        sm.s.sorted[p] = (uint32)src[e] | ((uint32)(d & (TILE - 1)) << 24);
        sm.s.bid[p] = (unsigned short)b;
      }
    }
    __syncthreads();
    for (int i = t; i < ne; i += NF) {
      int b = sm.s.bid[i];
      int g = sm.s.delta[b] + i;  // = b*BSTRIDE + gbase[b] + local_rank
      if (g < ((b + 1) << BSTRIDE_SH))  // safety clamp (statistically unreachable)
        buck[g] = sm.s.sorted[i];
    }
    __syncthreads();  // scatter LDS dead; safe to overwrite with Wt
  }
  // --- static GEMM tile assignment ---
  stage_W<128, NF>(W1, sm.wt);
  __syncthreads();
  if (isScat) {
    // scatter blocks sweep the tail [t0, ntile) -- starts late, small share
    for (int tile = t0 + (int)blockIdx.x; tile < ntile; tile += gscat)
      gemm_tile8<128>(X, sm.wt, Yb, n, tile * GTILE);
  } else {
    // gemm blocks grid-stride [0, t0) -- start immediately
    const int gg = gridDim.x - gscat;
    for (int tile = (int)blockIdx.x - gscat; tile < t0; tile += gg)
      gemm_tile8<128>(X, sm.wt, Yb, n, tile * GTILE);
  }
}

// One block (1024 thr, 16 waves) per bucket: LDS hist -> scan ->
// rowspan{beg,end}/dinv; bucket-local srcs SORTED IN LDS then written out
// contiguously (coalesced). 16 waves/block -> ~24 waves/CU at 391 blocks.
__global__ __launch_bounds__(NB) void k_bcsr(const uint32* __restrict__ buck,
                                             const int* __restrict__ bcursor,
                                             int2* __restrict__ rowspan,
                                             float* __restrict__ dinv,
                                             int* __restrict__ srcs, int n) {
  __shared__ int hist[TILE];
  __shared__ int hs[TILE];
  __shared__ int off[TILE];
  __shared__ uint32 sarr[BSTRIDE];
  const int b = blockIdx.x;
  const int t = threadIdx.x;
  const int W = b * BSTRIDE;
  const int cntb = min(bcursor[b], BSTRIDE);
  const int v0 = b << TILE_SH;
  const int nv = min(TILE, n - v0);
  if (t < TILE) hist[t] = 0;
  __syncthreads();
  for (int i = t; i < cntb; i += NB) atomicAdd(&hist[buck[W + i] >> 24], 1);
  __syncthreads();
  int h = (t < TILE) ? hist[t] : 0;
  if (t < TILE) hs[t] = h;
  __syncthreads();
  for (int o = 1; o < TILE; o <<= 1) {
    int x = (t >= o && t < TILE) ? hs[t - o] : 0;
    __syncthreads();
    if (t < TILE) hs[t] += x;
    __syncthreads();
  }
  if (t < TILE) {
    int ex = hs[t] - h;
    off[t] = ex;
    if (t < nv) {
      rowspan[v0 + t] = make_int2(W + ex, W + ex + h);
      dinv[v0 + t] = rsqrtf((float)(h + 1));
    }
  }
  __syncthreads();
  for (int i = t; i < cntb; i += NB) {
    uint32 w = buck[W + i];
    int ld = (int)(w >> 24);
    int p = atomicAdd(&off[ld], 1);  // p < cntb <= BSTRIDE
    sarr[p] = w & 0x00FFFFFFu;
  }
  __syncthreads();
  for (int i = t; i < cntb; i += NB) srcs[W + i] = (int)sarr[i];
}

struct Acc8 {
  float a0, a1, a2, a3, a4, a5, a6, a7;
  __device__ __forceinline__ void madd(uint4 r, float s) {
    a0 = fmaf(bflo(r.x), s, a0); a1 = fmaf(bfhi(r.x), s, a1);
    a2 = fmaf(bflo(r.y), s, a2); a3 = fmaf(bfhi(r.y), s, a3);
    a4 = fmaf(bflo(r.z), s, a4); a5 = fmaf(bfhi(r.z), s, a5);
    a6 = fmaf(bflo(r.w), s, a6); a7 = fmaf(bfhi(r.w), s, a7);
  }
};

// Aggregation core for one node: 8 lanes x uint4 per row, q in [0,4) edge
// slots, 4-deep unroll => 16 independent {srcs,dinv,row} chains in flight per
// 32-lane group. MEASURED OPTIMUM: the round-12 shuffle-fed variant (single-
// level chain, 32 loads upfront) was 18% SLOWER with +20% HBM traffic --
// extra concurrency thrashed L2. Chain depth is not the binding constraint;
// cache pressure is. Do not re-attempt without a traffic-reduction mechanism.
__device__ __forceinline__ void agg_node(const int* __restrict__ srcs,
                                         const float* __restrict__ dinv,
                                         const uint4* __restrict__ Y, int beg,
                                         int end, int part, int q, Acc8& A) {
  int j = beg + q;
  for (; j + 12 < end; j += 16) {
    int s0 = srcs[j];
    int s1 = srcs[j + 4];
    int s2 = srcs[j + 8];
    int s3 = srcs[j + 12];
    float d0 = dinv[s0], d1 = dinv[s1], d2 = dinv[s2], d3 = dinv[s3];
    uint4 r0 = Y[(size_t)s0 * 8 + part];
    uint4 r1 = Y[(size_t)s1 * 8 + part];
    uint4 r2 = Y[(size_t)s2 * 8 + part];
    uint4 r3 = Y[(size_t)s3 * 8 + part];
    A.madd(r0, d0);
    A.madd(r1, d1);
    A.madd(r2, d2);
    A.madd(r3, d3);
  }
  if (j + 4 < end) {
    int s0 = srcs[j];
    int s1 = srcs[j + 4];
    float d0 = dinv[s0], d1 = dinv[s1];
    uint4 r0 = Y[(size_t)s0 * 8 + part];
    uint4 r1 = Y[(size_t)s1 * 8 + part];
    A.madd(r0, d0);
    A.madd(r1, d1);
    j += 8;
  }
  if (j < end) {
    int s = srcs[j];
    A.madd(Y[(size_t)s * 8 + part], dinv[s]);
  }
}

#define L1STR 72  // 64 + 8 pad (shorts); 144 B row, 16B-aligned

// ---- layer-1 aggregate + MFMA layer-2 transform, one block = 32 nodes ----
// 256 thr / 4 waves, grid 3125 (n = 3125*32 exactly): 13.8 KB LDS ->
// 8 blocks/CU x 4 waves = full 32-wave residency. The 4 node-passes are now
// FULLY UNROLLED with all rowspan/dinv loads HOISTED upfront (12 VGPRs,
// statically indexed): pass p+1's srcs/row chains can issue under pass p's
// tail instead of waiting on a fresh rowspan round-trip (3 exposed chain
// starts eliminated). Row-load concurrency per pass unchanged (the round-12
// lesson: more row MLP thrashes L2 -- this adds only 4 tiny loads).
// Accumulation order identical -> bit-identical output.  (NT,8): 64-VGPR cap.
__global__ __launch_bounds__(NT, 8) void k_gather_l1(
    const int2* __restrict__ rowspan, const int* __restrict__ srcs,
    const float* __restrict__ dinv, const uint4* __restrict__ Y1,
    const float* __restrict__ bias, const float* __restrict__ W2,
    uint2* __restrict__ Y2, int n) {
  __shared__ unsigned short Wt[64 * L1STR];  // 9216 B
  __shared__ unsigned short Hs[32 * L1STR];  // 4608 B
  stage_W<64, NT>(W2, Wt);

  const int tid = threadIdx.x;
  const int lane = tid & 63;
  const int l5 = lane & 31;
  const int part = l5 & 7;
  const int q = l5 >> 3;
  const int grp = ((tid >> 6) << 1) + (lane >> 5);  // node group 0..7
  const int base = blockIdx.x * 32;

  // hoisted per-pass node metadata (static indexing -- both loops unrolled)
  int2 rsArr[4];
  float dvArr[4];
#pragma unroll
  for (int p = 0; p < 4; ++p) {
    const int v = base + p * 8 + grp;
    const bool act = v < n;
    rsArr[p] = act ? rowspan[v] : make_int2(0, 0);
    dvArr[p] = act ? dinv[v] : 0.f;
  }

#pragma unroll
  for (int p = 0; p < 4; ++p) {
    const int local = p * 8 + grp;
    const int v = base + local;
    const bool act = v < n;
    const int2 rs = rsArr[p];
    const float dv = dvArr[p];
    uint4 wv = act ? Y1[(size_t)v * 8 + part] : make_uint4(0u, 0u, 0u, 0u);
    Acc8 A = {0.f, 0.f, 0.f, 0.f, 0.f, 0.f, 0.f, 0.f};
    agg_node(srcs, dinv, Y1, rs.x, rs.y, part, q, A);
#pragma unroll
    for (int m = 8; m <= 16; m <<= 1) {
      A.a0 += __shfl_xor(A.a0, m);
      A.a1 += __shfl_xor(A.a1, m);
      A.a2 += __shfl_xor(A.a2, m);
      A.a3 += __shfl_xor(A.a3, m);
      A.a4 += __shfl_xor(A.a4, m);
      A.a5 += __shfl_xor(A.a5, m);
      A.a6 += __shfl_xor(A.a6, m);
      A.a7 += __shfl_xor(A.a7, m);
    }
    if (q == 0 && act) {
      const float4* b4 = (const float4*)bias;
      float4 b0 = b4[part * 2], b1 = b4[part * 2 + 1];
      float r0 = fmaxf(dv * (A.a0 + dv * bflo(wv.x)) + b0.x, 0.f);
      float r1 = fmaxf(dv * (A.a1 + dv * bfhi(wv.x)) + b0.y, 0.f);
      float r2 = fmaxf(dv * (A.a2 + dv * bflo(wv.y)) + b0.z, 0.f);
      float r3 = fmaxf(dv * (A.a3 + dv * bfhi(wv.y)) + b0.w, 0.f);
      float r4 = fmaxf(dv * (A.a4 + dv * bflo(wv.z)) + b1.x, 0.f);
      float r5 = fmaxf(dv * (A.a5 + dv * bfhi(wv.z)) + b1.y, 0.f);
      float r6 = fmaxf(dv * (A.a6 + dv * bflo(wv.w)) + b1.z, 0.f);
      float r7 = fmaxf(dv * (A.a7 + dv * bfhi(wv.w)) + b1.w, 0.f);
      uint4 u;
      u.x = (uint32)f2bf(r0) | ((uint32)f2bf(r1) << 16);
      u.y = (uint32)f2bf(r2) | ((uint32)f2bf(r3) << 16);
      u.z = (uint32)f2bf(r4) | ((uint32)f2bf(r5) << 16);
      u.w = (uint32)f2bf(r6) | ((uint32)f2bf(r7) << 16);
      *(uint4*)&Hs[local * L1STR + part * 8] = u;
    }
  }
  __syncthreads();
  gemm_tile_lds4<64>(Hs, Wt, Y2, n, base);
}

// Final gather: out = dv*(sum_s dinv[s]*Y2[s] + dv*Y2[v]) + b2, fp32 out.
__global__ __launch_bounds__(NT, 8) void k_gather2(const int2* __restrict__ rowspan,
                                                   const int* __restrict__ srcs,
                                                   const float* __restrict__ dinv,
                                                   const uint4* __restrict__ Xn,
                                                   const float* __restrict__ bias,
                                                   float* __restrict__ outp, int n) {
  const int gt = blockIdx.x * NT + threadIdx.x;
  const int lane = threadIdx.x & 63;
  const int v = ((gt >> 6) << 1) + (lane >> 5);
  if (v >= n) return;
  const int l5 = lane & 31;
  const int part = l5 & 7;
  const int q = l5 >> 3;
  const int2 rs = rowspan[v];
  const float dv = dinv[v];
  uint4 wv = Xn[(size_t)v * 8 + part];
  Acc8 A = {0.f, 0.f, 0.f, 0.f, 0.f, 0.f, 0.f, 0.f};
  agg_node(srcs, dinv, Xn, rs.x, rs.y, part, q, A);
#pragma unroll
  for (int m = 8; m <= 16; m <<= 1) {
    A.a0 += __shfl_xor(A.a0, m);
    A.a1 += __shfl_xor(A.a1, m);
    A.a2 += __shfl_xor(A.a2, m);
    A.a3 += __shfl_xor(A.a3, m);
    A.a4 += __shfl_xor(A.a4, m);
    A.a5 += __shfl_xor(A.a5, m);
    A.a6 += __shfl_xor(A.a6, m);
    A.a7 += __shfl_xor(A.a7, m);
  }
  if (q == 0) {
    const float4* b4 = (const float4*)bias;
    float4 b0 = b4[part * 2], b1 = b4[part * 2 + 1];
    float r0 = dv * (A.a0 + dv * bflo(wv.x)) + b0.x;
    float r1 = dv * (A.a1 + dv * bfhi(wv.x)) + b0.y;
    float r2 = dv * (A.a2 + dv * bflo(wv.y)) + b0.z;
    float r3 = dv * (A.a3 + dv * bfhi(wv.y)) + b0.w;
    float r4 = dv * (A.a4 + dv * bflo(wv.z)) + b1.x;
    float r5 = dv * (A.a5 + dv * bfhi(wv.z)) + b1.y;
    float r6 = dv * (A.a6 + dv * bflo(wv.w)) + b1.z;
    float r7 = dv * (A.a7 + dv * bfhi(wv.w)) + b1.w;
    float4* o4 = (float4*)outp;
    o4[(size_t)v * 16 + part * 2] = make_float4(r0, r1, r2, r3);
    o4[(size_t)v * 16 + part * 2 + 1] = make_float4(r4, r5, r6, r7);
  }
}

extern "C" void kernel_launch(void* const* d_in, const int* in_sizes, int n_in,
                              void* d_out, int out_size, void* d_ws, size_t ws_size,
                              hipStream_t stream) {
  // setup_inputs order: V, E, X, W1, b1, W2, b2
  const int* E = (const int*)d_in[1];
  const float* X = (const float*)d_in[2];
  const float* W1 = (const float*)d_in[3];
  const float* b1 = (const float*)d_in[4];
  const float* W2 = (const float*)d_in[5];
  const float* b2 = (const float*)d_in[6];
  float* out = (float*)d_out;

  const int n = in_sizes[2] / 128;  // 100000
  const int nE = in_sizes[1] / 2;   // 1600000
  const int* src = E;
  const int* dst = E + nE;
  const int nbuck = cdiv(n, TILE);  // 391

  char* ws = (char*)d_ws;
  size_t off = 0;
  auto alloc = [&](size_t bytes) {
    size_t o = off;
    off = (off + bytes + 255) & ~(size_t)255;
    return (void*)(ws + o);
  };
  int2* rowspan = (int2*)alloc((size_t)n * 8);
  float* dinv = (float*)alloc((size_t)n * 4);
  int* bcursor = (int*)alloc((size_t)nbuck * 4);
  uint32* buck = (uint32*)alloc((size_t)nbuck * BSTRIDE * 4);
  int* srcs = (int*)alloc((size_t)nbuck * BSTRIDE * 4);
  uint2* Y1 = (uint2*)alloc((size_t)n * 64 * 2);  // bf16 rows, 128 B each
  uint2* Y2 = (uint2*)alloc((size_t)n * 64 * 2);  // bf16 rows, 128 B each

  const int gscat = cdiv(nE, EPB);      // 391
  const int ntile = cdiv(n, GTILE);     // 782 (128-node tiles)
  const int gfused = 1024;              // 4 blocks/CU at 32 KB LDS, 512 thr
  const int ggemm = gfused - gscat;     // 633
  const int T0 = ggemm;                 // gemm blocks get exactly 1 tile each
  const int ntile32 = cdiv(n, 32);      // 3125 (gather_l1 tiles)
  const int gthreads_blocks = cdiv((long long)n * 32, NT);  // 12500 (exact)

  hipMemsetAsync(bcursor, 0, (size_t)nbuck * 4, stream);

  // --- CSR scatter (8-wave blocks) + layer-1 GEMM, static partition ---
  k_fused<<<gfused, NF, 0, stream>>>(src, dst, bcursor, buck, nE, nbuck, gscat,
                                     T0, ntile, X, W1, Y1, n);
  k_bcsr<<<nbuck, NB, 0, stream>>>(buck, bcursor, rowspan, dinv, srcs, n);

  // --- layer-1 aggregate + MFMA layer-2 transform (writes Y2 directly) ---
  k_gather_l1<<<ntile32, NT, 0, stream>>>(rowspan, srcs, dinv, (const uint4*)Y1,
                                          b1, W2, Y2, n);

  // --- final aggregate ---
  k_gather2<<<gthreads_blocks, NT, 0, stream>>>(rowspan, srcs, dinv,
                                                (const uint4*)Y2, b2, out, n);
}

// Round 15
// 213.698 us; speedup vs baseline: 1.0189x; 1.0189x over previous
//
#include <hip/hip_runtime.h>

#define NT 256
#define NF 512        // threads for fused scatter+gemm (8 waves)
#define NB 1024       // threads for bcsr (16 waves)
#define TILE 256      // nodes per bucket
#define TILE_SH 8
#define BSTRIDE 8192  // padded edge slots per bucket (mean 4096, sigma 64)
#define BSTRIDE_SH 13
#define EPB 4096      // edges per block in bucket scatter pass
#define ITB 8         // EPB / NF
#define NBUCK_PAD 512
#define GTILE 128     // nodes per fused-gemm tile (8 waves x 16 rows)

static inline int cdiv(long long a, long long b) { return (int)((a + b - 1) / b); }

typedef unsigned int uint32;
typedef unsigned short ushort16;
typedef short bf16x8 __attribute__((ext_vector_type(8)));
typedef float f32x4 __attribute__((ext_vector_type(4)));

__device__ __forceinline__ ushort16 f2bf(float f) {
  uint32 u = __float_as_uint(f);
  u = (u + 0x7FFF + ((u >> 16) & 1)) >> 16;  // round-to-nearest-even
  return (ushort16)u;
}
__device__ __forceinline__ float bflo(uint32 w) { return __uint_as_float(w << 16); }
__device__ __forceinline__ float bfhi(uint32 w) { return __uint_as_float(w & 0xFFFF0000u); }
__device__ __forceinline__ float bf2f(ushort16 h) { return __uint_as_float(((uint32)h) << 16); }

// stage W (fp32 [k][64]) -> bf16 transposed Wt[n][k], row stride K+8
template <int K, int NTH>
__device__ __forceinline__ void stage_W(const float* __restrict__ W,
                                        unsigned short* __restrict__ Wt) {
  constexpr int STR = K + 8;
  for (int i = threadIdx.x; i < K * 64; i += NTH) {
    int k = i >> 6, nn = i & 63;
    Wt[nn * STR + k] = f2bf(W[i]);
  }
}

// ---- MFMA GEMM tile for 512-thr blocks: 128 nodes (wave w -> rows w*16..+16),
// fp32 X direct-to-register + hi/lo bf16 split, 2 chained MFMAs.
// D = mfma(W_frag, X_frag): C/D col (lane&15) = node, row (quad*4+reg) = out-dim.
// No cross-wave coupling and no barriers: waves pipeline tiles independently.
template <int K>
__device__ __forceinline__ void gemm_tile8(const float* __restrict__ Xp,
                                           const unsigned short* __restrict__ Wt,
                                           uint2* __restrict__ Yb, int n, int base) {
  constexpr int STR = K + 8;
  const int tid = threadIdx.x;
  const int w = tid >> 6;  // 0..7
  const int lane = tid & 63;
  const int r = lane & 15;
  const int quad = lane >> 4;
  const int v = base + w * 16 + r;

  f32x4 acc[4];
#pragma unroll
  for (int i = 0; i < 4; ++i) acc[i] = (f32x4)(0.f);

  const float4* X4 = (const float4*)Xp;  // K/4 float4 per row
  float4 a[K / 32][2];
#pragma unroll
  for (int ks = 0; ks < K / 32; ++ks) {
    a[ks][0] = make_float4(0.f, 0.f, 0.f, 0.f);
    a[ks][1] = make_float4(0.f, 0.f, 0.f, 0.f);
    if (v < n) {
      a[ks][0] = X4[(size_t)v * (K / 4) + ks * 8 + quad * 2];
      a[ks][1] = X4[(size_t)v * (K / 4) + ks * 8 + quad * 2 + 1];
    }
  }
#pragma unroll
  for (int ks = 0; ks < K / 32; ++ks) {
    float f[8] = {a[ks][0].x, a[ks][0].y, a[ks][0].z, a[ks][0].w,
                  a[ks][1].x, a[ks][1].y, a[ks][1].z, a[ks][1].w};
    bf16x8 xh, xl;
#pragma unroll
    for (int j = 0; j < 8; ++j) {
      ushort16 h = f2bf(f[j]);
      xh[j] = (short)h;
      xl[j] = (short)f2bf(f[j] - bf2f(h));
    }
    const int koff = ks * 32 + quad * 8;
#pragma unroll
    for (int nt = 0; nt < 4; ++nt) {
      bf16x8 wf = *(const bf16x8*)&Wt[(nt * 16 + r) * STR + koff];
      acc[nt] = __builtin_amdgcn_mfma_f32_16x16x32_bf16(wf, xl, acc[nt], 0, 0, 0);
      acc[nt] = __builtin_amdgcn_mfma_f32_16x16x32_bf16(wf, xh, acc[nt], 0, 0, 0);
    }
  }

  if (v < n) {
#pragma unroll
    for (int nt = 0; nt < 4; ++nt) {
      // reg i holds out-dim nt*16 + quad*4 + i for node v
      uint2 u;
      u.x = (uint32)f2bf(acc[nt][0]) | ((uint32)f2bf(acc[nt][1]) << 16);
      u.y = (uint32)f2bf(acc[nt][2]) | ((uint32)f2bf(acc[nt][3]) << 16);
      Yb[(size_t)v * 16 + nt * 4 + quad] = u;
    }
  }
}

// ---- MFMA tile for 256-thr gather_l1 blocks (4 waves): 32 nodes.
// wave w -> row half (w&1), out-dim half (w>>1). A-rows (bf16) from LDS. ----
template <int K>
__device__ __forceinline__ void gemm_tile_lds4(const unsigned short* __restrict__ Hs,
                                               const unsigned short* __restrict__ Wt,
                                               uint2* __restrict__ Yb, int n,
                                               int base) {
  constexpr int STR = K + 8;
  const int tid = threadIdx.x;
  const int w = tid >> 6;   // 0..3
  const int wr = w & 1;     // row half
  const int nh = w >> 1;    // out-dim half
  const int lane = tid & 63;
  const int r = lane & 15;
  const int quad = lane >> 4;
  const int rloc = wr * 16 + r;
  const int v = base + rloc;

  f32x4 acc[2];
#pragma unroll
  for (int i = 0; i < 2; ++i) acc[i] = (f32x4)(0.f);
#pragma unroll
  for (int ks = 0; ks < K / 32; ++ks) {
    const int koff = ks * 32 + quad * 8;
    bf16x8 xf = *(const bf16x8*)&Hs[rloc * STR + koff];
#pragma unroll
    for (int i = 0; i < 2; ++i) {
      const int nt = nh * 2 + i;
      bf16x8 wf = *(const bf16x8*)&Wt[(nt * 16 + r) * STR + koff];
      acc[i] = __builtin_amdgcn_mfma_f32_16x16x32_bf16(wf, xf, acc[i], 0, 0, 0);
    }
  }
  if (v < n) {
#pragma unroll
    for (int i = 0; i < 2; ++i) {
      const int nt = nh * 2 + i;
      uint2 u;
      u.x = (uint32)f2bf(acc[i][0]) | ((uint32)f2bf(acc[i][1]) << 16);
      u.y = (uint32)f2bf(acc[i][2]) | ((uint32)f2bf(acc[i][3]) << 16);
      Yb[(size_t)v * 16 + nt * 4 + quad] = u;
    }
  }
}

struct ScatSh {
  int cnt[NBUCK_PAD];
  int lcur[NBUCK_PAD];
  int delta[NBUCK_PAD];
  int hs[NF];
  uint32 sorted[EPB];
  unsigned short bid[EPB];
};
union FusedSh {
  unsigned short wt[64 * 136];  // 17.4 KB
  ScatSh s;                     // 32 KB -> union 32 KB, 4 blocks/CU (128 KB LDS)
};

// Fused launch (grid 1024 x 512 thr, 4 blocks/CU = full 32-wave residency):
// blocks [0, gscat=391) do the bucketed edge scatter with 8 waves each, then
// statically sweep the GEMM tile tail [T0, ntile). Blocks [gscat, 1024)
// grid-stride GEMM tiles [0, T0) -- static assignment, zero steal traffic,
// zero barriers between tiles (measured fastest structure; block-chunk steal,
// per-wave steal, and EPB split all measured slower in rounds 6-8).
__global__ __launch_bounds__(NF) void k_fused(
    const int* __restrict__ src, const int* __restrict__ dst,
    int* __restrict__ bcursor, uint32* __restrict__ buck, int nE, int nbuck,
    int gscat, int t0, int ntile, const float* __restrict__ X,
    const float* __restrict__ W1, uint2* __restrict__ Yb, int n) {
  __shared__ FusedSh sm;
  const int t = threadIdx.x;
  const bool isScat = (int)blockIdx.x < gscat;
  if (isScat) {
    sm.s.cnt[t] = 0;
    __syncthreads();
    const int e0 = blockIdx.x * EPB;
    const int ne = min(EPB, nE - e0);
    int dreg[ITB];
#pragma unroll
    for (int it = 0; it < ITB; ++it) {
      int e = e0 + it * NF + t;
      dreg[it] = (e < nE) ? dst[e] : -1;
      if (dreg[it] >= 0) atomicAdd(&sm.s.cnt[dreg[it] >> TILE_SH], 1);
    }
    __syncthreads();
    // exclusive scan over 512 counters: one bucket per thread, Hillis-Steele
    int c = sm.s.cnt[t];
    sm.s.hs[t] = c;
    __syncthreads();
    for (int o = 1; o < NF; o <<= 1) {
      int x = (t >= o) ? sm.s.hs[t - o] : 0;
      __syncthreads();
      sm.s.hs[t] += x;
      __syncthreads();
    }
    int lb = sm.s.hs[t] - c;  // exclusive base of bucket t
    sm.s.lcur[t] = lb;
    if (t < nbuck) {
      int g = c ? atomicAdd(&bcursor[t], c) : 0;
      sm.s.delta[t] = (t << BSTRIDE_SH) + g - lb;
    }
    __syncthreads();
#pragma unroll
    for (int it = 0; it < ITB; ++it) {
      int e = e0 + it * NF + t;
      if (dreg[it] >= 0) {
        int d = dreg[it];
        int b = d >> TILE_SH;
        int p = atomicAdd(&sm.s.lcur[b], 1);  // p < ne <= EPB by construction
        sm.s.sorted[p] = (uint32)src[e] | ((uint32)(d & (TILE - 1)) << 24);
        sm.s.bid[p] = (unsigned short)b;
      }
    }
    __syncthreads();
    for (int i = t; i < ne; i += NF) {
      int b = sm.s.bid[i];
      int g = sm.s.delta[b] + i;  // = b*BSTRIDE + gbase[b] + local_rank
      if (g < ((b + 1) << BSTRIDE_SH))  // safety clamp (statistically unreachable)
        buck[g] = sm.s.sorted[i];
    }
    __syncthreads();  // scatter LDS dead; safe to overwrite with Wt
  }
  // --- static GEMM tile assignment ---
  stage_W<128, NF>(W1, sm.wt);
  __syncthreads();
  if (isScat) {
    // scatter blocks sweep the tail [t0, ntile) -- starts late, small share
    for (int tile = t0 + (int)blockIdx.x; tile < ntile; tile += gscat)
      gemm_tile8<128>(X, sm.wt, Yb, n, tile * GTILE);
  } else {
    // gemm blocks grid-stride [0, t0) -- start immediately
    const int gg = gridDim.x - gscat;
    for (int tile = (int)blockIdx.x - gscat; tile < t0; tile += gg)
      gemm_tile8<128>(X, sm.wt, Yb, n, tile * GTILE);
  }
}

// One block (1024 thr, 16 waves) per bucket: LDS hist -> scan ->
// rowspan{beg,end}/dinv; bucket-local srcs SORTED IN LDS then written out
// contiguously (coalesced). 16 waves/block -> ~24 waves/CU at 391 blocks.
__global__ __launch_bounds__(NB) void k_bcsr(const uint32* __restrict__ buck,
                                             const int* __restrict__ bcursor,
                                             int2* __restrict__ rowspan,
                                             float* __restrict__ dinv,
                                             int* __restrict__ srcs, int n) {
  __shared__ int hist[TILE];
  __shared__ int hs[TILE];
  __shared__ int off[TILE];
  __shared__ uint32 sarr[BSTRIDE];
  const int b = blockIdx.x;
  const int t = threadIdx.x;
  const int W = b * BSTRIDE;
  const int cntb = min(bcursor[b], BSTRIDE);
  const int v0 = b << TILE_SH;
  const int nv = min(TILE, n - v0);
  if (t < TILE) hist[t] = 0;
  __syncthreads();
  for (int i = t; i < cntb; i += NB) atomicAdd(&hist[buck[W + i] >> 24], 1);
  __syncthreads();
  int h = (t < TILE) ? hist[t] : 0;
  if (t < TILE) hs[t] = h;
  __syncthreads();
  for (int o = 1; o < TILE; o <<= 1) {
    int x = (t >= o && t < TILE) ? hs[t - o] : 0;
    __syncthreads();
    if (t < TILE) hs[t] += x;
    __syncthreads();
  }
  if (t < TILE) {
    int ex = hs[t] - h;
    off[t] = ex;
    if (t < nv) {
      rowspan[v0 + t] = make_int2(W + ex, W + ex + h);
      dinv[v0 + t] = rsqrtf((float)(h + 1));
    }
  }
  __syncthreads();
  for (int i = t; i < cntb; i += NB) {
    uint32 w = buck[W + i];
    int ld = (int)(w >> 24);
    int p = atomicAdd(&off[ld], 1);  // p < cntb <= BSTRIDE
    sarr[p] = w & 0x00FFFFFFu;
  }
  __syncthreads();
  for (int i = t; i < cntb; i += NB) srcs[W + i] = (int)sarr[i];
}

struct Acc8 {
  float a0, a1, a2, a3, a4, a5, a6, a7;
  __device__ __forceinline__ void madd(uint4 r, float s) {
    a0 = fmaf(bflo(r.x), s, a0); a1 = fmaf(bfhi(r.x), s, a1);
    a2 = fmaf(bflo(r.y), s, a2); a3 = fmaf(bfhi(r.y), s, a3);
    a4 = fmaf(bflo(r.z), s, a4); a5 = fmaf(bfhi(r.z), s, a5);
    a6 = fmaf(bflo(r.w), s, a6); a7 = fmaf(bfhi(r.w), s, a7);
  }
};

// Aggregation core for one node: 8 lanes x uint4 per row, q in [0,4) edge
// slots, 4-deep unroll => 16 independent {srcs,dinv,row} chains in flight per
// 32-lane group. MEASURED OPTIMUM (confirmed from both directions):
// - round-12 shuffle-fed (32 loads upfront): 18% slower, +20% HBM traffic.
// - round-14 hoisted/unrolled passes (cross-pass overlap): 6% slower,
//   FETCH +8%, WRITE +67%.
// Extra concurrency in any form thrashes L2; the serialized-pass, 16-chain
// form IS the equilibrium. Do not re-attempt without traffic reduction.
__device__ __forceinline__ void agg_node(const int* __restrict__ srcs,
                                         const float* __restrict__ dinv,
                                         const uint4* __restrict__ Y, int beg,
                                         int end, int part, int q, Acc8& A) {
  int j = beg + q;
  for (; j + 12 < end; j += 16) {
    int s0 = srcs[j];
    int s1 = srcs[j + 4];
    int s2 = srcs[j + 8];
    int s3 = srcs[j + 12];
    float d0 = dinv[s0], d1 = dinv[s1], d2 = dinv[s2], d3 = dinv[s3];
    uint4 r0 = Y[(size_t)s0 * 8 + part];
    uint4 r1 = Y[(size_t)s1 * 8 + part];
    uint4 r2 = Y[(size_t)s2 * 8 + part];
    uint4 r3 = Y[(size_t)s3 * 8 + part];
    A.madd(r0, d0);
    A.madd(r1, d1);
    A.madd(r2, d2);
    A.madd(r3, d3);
  }
  if (j + 4 < end) {
    int s0 = srcs[j];
    int s1 = srcs[j + 4];
    float d0 = dinv[s0], d1 = dinv[s1];
    uint4 r0 = Y[(size_t)s0 * 8 + part];
    uint4 r1 = Y[(size_t)s1 * 8 + part];
    A.madd(r0, d0);
    A.madd(r1, d1);
    j += 8;
  }
  if (j < end) {
    int s = srcs[j];
    A.madd(Y[(size_t)s * 8 + part], dinv[s]);
  }
}

#define L1STR 72  // 64 + 8 pad (shorts); 144 B row, 16B-aligned

// ---- layer-1 aggregate + MFMA layer-2 transform, one block = 32 nodes ----
// 256 thr / 4 waves, grid 3125 (n = 3125*32 exactly): 13.8 KB LDS ->
// 8 blocks/CU x 4 waves = full 32-wave residency. Per pass (4 serialized
// passes of 8 nodes -- serialization is load-throttling, keep it): aggregate
// + butterfly + epilogue (relu, bias) -> pack bf16 H row into LDS. One
// barrier, then the 4-wave 32x64x64 MFMA tile writes Y2 = bf16(H @ W2).
// (NT,8): 64-VGPR cap.
__global__ __launch_bounds__(NT, 8) void k_gather_l1(
    const int2* __restrict__ rowspan, const int* __restrict__ srcs,
    const float* __restrict__ dinv, const uint4* __restrict__ Y1,
    const float* __restrict__ bias, const float* __restrict__ W2,
    uint2* __restrict__ Y2, int n) {
  __shared__ unsigned short Wt[64 * L1STR];  // 9216 B
  __shared__ unsigned short Hs[32 * L1STR];  // 4608 B
  stage_W<64, NT>(W2, Wt);

  const int tid = threadIdx.x;
  const int lane = tid & 63;
  const int l5 = lane & 31;
  const int part = l5 & 7;
  const int q = l5 >> 3;
  const int grp = ((tid >> 6) << 1) + (lane >> 5);  // node group 0..7
  const int base = blockIdx.x * 32;

#pragma unroll 1
  for (int p = 0; p < 4; ++p) {
    const int local = p * 8 + grp;
    const int v = base + local;
    const bool act = v < n;
    int2 rs = act ? rowspan[v] : make_int2(0, 0);
    const float dv = act ? dinv[v] : 0.f;
    uint4 wv = act ? Y1[(size_t)v * 8 + part] : make_uint4(0u, 0u, 0u, 0u);
    Acc8 A = {0.f, 0.f, 0.f, 0.f, 0.f, 0.f, 0.f, 0.f};
    agg_node(srcs, dinv, Y1, rs.x, rs.y, part, q, A);
#pragma unroll
    for (int m = 8; m <= 16; m <<= 1) {
      A.a0 += __shfl_xor(A.a0, m);
      A.a1 += __shfl_xor(A.a1, m);
      A.a2 += __shfl_xor(A.a2, m);
      A.a3 += __shfl_xor(A.a3, m);
      A.a4 += __shfl_xor(A.a4, m);
      A.a5 += __shfl_xor(A.a5, m);
      A.a6 += __shfl_xor(A.a6, m);
      A.a7 += __shfl_xor(A.a7, m);
    }
    if (q == 0 && act) {
      const float4* b4 = (const float4*)bias;
      float4 b0 = b4[part * 2], b1 = b4[part * 2 + 1];
      float r0 = fmaxf(dv * (A.a0 + dv * bflo(wv.x)) + b0.x, 0.f);
      float r1 = fmaxf(dv * (A.a1 + dv * bfhi(wv.x)) + b0.y, 0.f);
      float r2 = fmaxf(dv * (A.a2 + dv * bflo(wv.y)) + b0.z, 0.f);
      float r3 = fmaxf(dv * (A.a3 + dv * bfhi(wv.y)) + b0.w, 0.f);
      float r4 = fmaxf(dv * (A.a4 + dv * bflo(wv.z)) + b1.x, 0.f);
      float r5 = fmaxf(dv * (A.a5 + dv * bfhi(wv.z)) + b1.y, 0.f);
      float r6 = fmaxf(dv * (A.a6 + dv * bflo(wv.w)) + b1.z, 0.f);
      float r7 = fmaxf(dv * (A.a7 + dv * bfhi(wv.w)) + b1.w, 0.f);
      uint4 u;
      u.x = (uint32)f2bf(r0) | ((uint32)f2bf(r1) << 16);
      u.y = (uint32)f2bf(r2) | ((uint32)f2bf(r3) << 16);
      u.z = (uint32)f2bf(r4) | ((uint32)f2bf(r5) << 16);
      u.w = (uint32)f2bf(r6) | ((uint32)f2bf(r7) << 16);
      *(uint4*)&Hs[local * L1STR + part * 8] = u;
    }
  }
  __syncthreads();
  gemm_tile_lds4<64>(Hs, Wt, Y2, n, base);
}

// Final gather: out = dv*(sum_s dinv[s]*Y2[s] + dv*Y2[v]) + b2, fp32 out.
__global__ __launch_bounds__(NT, 8) void k_gather2(const int2* __restrict__ rowspan,
                                                   const int* __restrict__ srcs,
                                                   const float* __restrict__ dinv,
                                                   const uint4* __restrict__ Xn,
                                                   const float* __restrict__ bias,
                                                   float* __restrict__ outp, int n) {
  const int gt = blockIdx.x * NT + threadIdx.x;
  const int lane = threadIdx.x & 63;
  const int v = ((gt >> 6) << 1) + (lane >> 5);
  if (v >= n) return;
  const int l5 = lane & 31;
  const int part = l5 & 7;
  const int q = l5 >> 3;
  const int2 rs = rowspan[v];
  const float dv = dinv[v];
  uint4 wv = Xn[(size_t)v * 8 + part];
  Acc8 A = {0.f, 0.f, 0.f, 0.f, 0.f, 0.f, 0.f, 0.f};
  agg_node(srcs, dinv, Xn, rs.x, rs.y, part, q, A);
#pragma unroll
  for (int m = 8; m <= 16; m <<= 1) {
    A.a0 += __shfl_xor(A.a0, m);
    A.a1 += __shfl_xor(A.a1, m);
    A.a2 += __shfl_xor(A.a2, m);
    A.a3 += __shfl_xor(A.a3, m);
    A.a4 += __shfl_xor(A.a4, m);
    A.a5 += __shfl_xor(A.a5, m);
    A.a6 += __shfl_xor(A.a6, m);
    A.a7 += __shfl_xor(A.a7, m);
  }
  if (q == 0) {
    const float4* b4 = (const float4*)bias;
    float4 b0 = b4[part * 2], b1 = b4[part * 2 + 1];
    float r0 = dv * (A.a0 + dv * bflo(wv.x)) + b0.x;
    float r1 = dv * (A.a1 + dv * bfhi(wv.x)) + b0.y;
    float r2 = dv * (A.a2 + dv * bflo(wv.y)) + b0.z;
    float r3 = dv * (A.a3 + dv * bfhi(wv.y)) + b0.w;
    float r4 = dv * (A.a4 + dv * bflo(wv.z)) + b1.x;
    float r5 = dv * (A.a5 + dv * bfhi(wv.z)) + b1.y;
    float r6 = dv * (A.a6 + dv * bflo(wv.w)) + b1.z;
    float r7 = dv * (A.a7 + dv * bfhi(wv.w)) + b1.w;
    float4* o4 = (float4*)outp;
    o4[(size_t)v * 16 + part * 2] = make_float4(r0, r1, r2, r3);
    o4[(size_t)v * 16 + part * 2 + 1] = make_float4(r4, r5, r6, r7);
  }
}

extern "C" void kernel_launch(void* const* d_in, const int* in_sizes, int n_in,
                              void* d_out, int out_size, void* d_ws, size_t ws_size,
                              hipStream_t stream) {
  // setup_inputs order: V, E, X, W1, b1, W2, b2
  const int* E = (const int*)d_in[1];
  const float* X = (const float*)d_in[2];
  const float* W1 = (const float*)d_in[3];
  const float* b1 = (const float*)d_in[4];
  const float* W2 = (const float*)d_in[5];
  const float* b2 = (const float*)d_in[6];
  float* out = (float*)d_out;

  const int n = in_sizes[2] / 128;  // 100000
  const int nE = in_sizes[1] / 2;   // 1600000
  const int* src = E;
  const int* dst = E + nE;
  const int nbuck = cdiv(n, TILE);  // 391

  char* ws = (char*)d_ws;
  size_t off = 0;
  auto alloc = [&](size_t bytes) {
    size_t o = off;
    off = (off + bytes + 255) & ~(size_t)255;
    return (void*)(ws + o);
  };
  int2* rowspan = (int2*)alloc((size_t)n * 8);
  float* dinv = (float*)alloc((size_t)n * 4);
  int* bcursor = (int*)alloc((size_t)nbuck * 4);
  uint32* buck = (uint32*)alloc((size_t)nbuck * BSTRIDE * 4);
  int* srcs = (int*)alloc((size_t)nbuck * BSTRIDE * 4);
  uint2* Y1 = (uint2*)alloc((size_t)n * 64 * 2);  // bf16 rows, 128 B each
  uint2* Y2 = (uint2*)alloc((size_t)n * 64 * 2);  // bf16 rows, 128 B each

  const int gscat = cdiv(nE, EPB);      // 391
  const int ntile = cdiv(n, GTILE);     // 782 (128-node tiles)
  const int gfused = 1024;              // 4 blocks/CU at 32 KB LDS, 512 thr
  const int ggemm = gfused - gscat;     // 633
  const int T0 = ggemm;                 // gemm blocks get exactly 1 tile each
  const int ntile32 = cdiv(n, 32);      // 3125 (gather_l1 tiles)
  const int gthreads_blocks = cdiv((long long)n * 32, NT);  // 12500 (exact)

  hipMemsetAsync(bcursor, 0, (size_t)nbuck * 4, stream);

  // --- CSR scatter (8-wave blocks) + layer-1 GEMM, static partition ---
  k_fused<<<gfused, NF, 0, stream>>>(src, dst, bcursor, buck, nE, nbuck, gscat,
                                     T0, ntile, X, W1, Y1, n);
  k_bcsr<<<nbuck, NB, 0, stream>>>(buck, bcursor, rowspan, dinv, srcs, n);

  // --- layer-1 aggregate + MFMA layer-2 transform (writes Y2 directly) ---
  k_gather_l1<<<ntile32, NT, 0, stream>>>(rowspan, srcs, dinv, (const uint4*)Y1,
                                          b1, W2, Y2, n);

  // --- final aggregate ---
  k_gather2<<<gthreads_blocks, NT, 0, stream>>>(rowspan, srcs, dinv,
                                                (const uint4*)Y2, b2, out, n);
}